// Round 2
// baseline (4512.861 us; speedup 1.0000x reference)
//
#include <hip/hip_runtime.h>
#include <hip/hip_bf16.h>

#define NTOK 131072
#define DIM 512
#define MSLOT 25
#define TB 16
#define ALPHA 0.2f
#define MOMENTUM 0.8f

typedef unsigned int u32;

// order-preserving float<->uint for atomicMax on signed floats
__device__ __forceinline__ u32 f2sort(float f) {
    u32 u = __float_as_uint(f);
    return (u & 0x80000000u) ? ~u : (u | 0x80000000u);
}
__device__ __forceinline__ float sort2f(u32 u) {
    return __uint_as_float((u & 0x80000000u) ? (u ^ 0x80000000u) : ~u);
}

// ---------------- G = cache @ W2^T   (G[j][o] = sum_k cache[j,k] * W[o,512+k]) ----------------
__global__ __launch_bounds__(256) void k_G(const float* __restrict__ W,
                                           const float* __restrict__ C,
                                           float* __restrict__ G) {
    int gid = blockIdx.x * 256 + threadIdx.x;
    if (gid >= MSLOT * DIM) return;
    int j = gid >> 9, o = gid & (DIM - 1);
    const float4* c4 = (const float4*)(C + j * DIM);
    const float4* w4 = (const float4*)(W + (size_t)o * (2 * DIM) + DIM);
    float acc = 0.f;
    for (int kc = 0; kc < DIM / 4; kc++) {
        float4 cv = c4[kc], wv = w4[kc];
        acc += cv.x * wv.x + cv.y * wv.y + cv.z * wv.z + cv.w * wv.w;
    }
    G[j * DIM + o] = acc;
}

// ---------------- text path: normalize -> scores -> softmax -> 0.2*(T@W1^T + P@G) + T, loss ----------------
__global__ __launch_bounds__(256) void k_A(const float* __restrict__ T,
                                           const float* __restrict__ W,
                                           const float* __restrict__ C,
                                           const float* __restrict__ G,
                                           float* __restrict__ out,
                                           float* __restrict__ loss_acc) {
    __shared__ __align__(16) float t_flat[TB * DIM];
    __shared__ float sp[TB * MSLOT];
    __shared__ float nrm[TB];
    __shared__ float red[TB];
    const int tid = threadIdx.x;
    const size_t base = (size_t)blockIdx.x * (TB * DIM);

    // stage 16 token rows into LDS
    const float4* src = (const float4*)(T + base);
    float4* dst = (float4*)t_flat;
    for (int v = tid; v < TB * DIM / 4; v += 256) dst[v] = src[v];
    __syncthreads();
    // row norms (16 threads per token)
    {
        int tt = tid >> 4, l = tid & 15;
        float ss = 0.f;
        for (int c = l; c < DIM; c += 16) { float x = t_flat[tt * DIM + c]; ss += x * x; }
        ss += __shfl_xor(ss, 8, 16);
        ss += __shfl_xor(ss, 4, 16);
        ss += __shfl_xor(ss, 2, 16);
        ss += __shfl_xor(ss, 1, 16);
        if (l == 0) nrm[tt] = sqrtf(ss);
    }
    __syncthreads();
    // scores s[tt][j] = (t . cache_j) / max(||t||,eps)
    for (int pr = tid; pr < TB * MSLOT; pr += 256) {
        int tt = pr / MSLOT, j = pr - tt * MSLOT;
        const float4* c4 = (const float4*)(C + j * DIM);
        const float4* tp = (const float4*)&t_flat[tt * DIM];
        float acc = 0.f;
        for (int kc = 0; kc < DIM / 4; kc++) {
            float4 cv = c4[kc], q = tp[kc];
            acc += cv.x * q.x + cv.y * q.y + cv.z * q.z + cv.w * q.w;
        }
        sp[pr] = acc / fmaxf(nrm[tt], 1e-12f);
    }
    __syncthreads();
    // softmax over 25 slots (one thread per token)
    if (tid < TB) {
        float m = -1e30f;
        for (int j = 0; j < MSLOT; j++) m = fmaxf(m, sp[tid * MSLOT + j]);
        float s = 0.f;
        for (int j = 0; j < MSLOT; j++) { float e = expf(sp[tid * MSLOT + j] - m); sp[tid * MSLOT + j] = e; s += e; }
        float inv = 1.0f / s;
        for (int j = 0; j < MSLOT; j++) sp[tid * MSLOT + j] *= inv;
    }
    __syncthreads();
    // GEMV: each thread owns output cols o0, o0+1 for all 16 tokens
    float acc0[TB], acc1[TB];
#pragma unroll
    for (int tt = 0; tt < TB; tt++) { acc0[tt] = 0.f; acc1[tt] = 0.f; }
    const int o0 = tid * 2;
    const float4* w0 = (const float4*)(W + (size_t)o0 * (2 * DIM));
    const float4* w1 = (const float4*)(W + (size_t)(o0 + 1) * (2 * DIM));
    for (int kc = 0; kc < DIM / 8; kc++) {
        float4 wa0 = w0[2 * kc], wa1 = w0[2 * kc + 1];
        float4 wb0 = w1[2 * kc], wb1 = w1[2 * kc + 1];
#pragma unroll
        for (int tt = 0; tt < TB; tt++) {
            const float* q = &t_flat[tt * DIM + kc * 8];
            float4 q0 = *(const float4*)q;
            float4 q1 = *(const float4*)(q + 4);
            acc0[tt] += wa0.x * q0.x + wa0.y * q0.y + wa0.z * q0.z + wa0.w * q0.w
                      + wa1.x * q1.x + wa1.y * q1.y + wa1.z * q1.z + wa1.w * q1.w;
            acc1[tt] += wb0.x * q0.x + wb0.y * q0.y + wb0.z * q0.z + wb0.w * q0.w
                      + wb1.x * q1.x + wb1.y * q1.y + wb1.z * q1.z + wb1.w * q1.w;
        }
    }
    // fine contribution via G (rank-25)
    for (int j = 0; j < MSLOT; j++) {
        float g0 = G[j * DIM + o0], g1 = G[j * DIM + o0 + 1];
#pragma unroll
        for (int tt = 0; tt < TB; tt++) {
            float pj = sp[tt * MSLOT + j];
            acc0[tt] += pj * g0; acc1[tt] += pj * g1;
        }
    }
#pragma unroll
    for (int tt = 0; tt < TB; tt++) {
        acc0[tt] = ALPHA * acc0[tt] + t_flat[tt * DIM + o0];
        acc1[tt] = ALPHA * acc1[tt] + t_flat[tt * DIM + o0 + 1];
    }
    // per-token ||text_fine|| for the loss
    if (tid < TB) red[tid] = 0.f;
    __syncthreads();
#pragma unroll
    for (int tt = 0; tt < TB; tt++) atomicAdd(&red[tt], acc0[tt] * acc0[tt] + acc1[tt] * acc1[tt]);
    __syncthreads();
    float lp = 0.f;
#pragma unroll
    for (int tt = 0; tt < TB; tt++) {
        float inv = 1.0f / fmaxf(sqrtf(red[tt]), 1e-12f);
        lp += fabsf(acc0[tt] * inv - t_flat[tt * DIM + o0])
            + fabsf(acc1[tt] * inv - t_flat[tt * DIM + o0 + 1]);
        size_t oi = base + (size_t)tt * DIM + o0;
        out[oi]     = acc0[tt];
        out[oi + 1] = acc1[tt];
    }
    lp += __shfl_xor(lp, 32, 64); lp += __shfl_xor(lp, 16, 64);
    lp += __shfl_xor(lp, 8, 64);  lp += __shfl_xor(lp, 4, 64);
    lp += __shfl_xor(lp, 2, 64);  lp += __shfl_xor(lp, 1, 64);
    if ((tid & 63) == 0) atomicAdd(loss_acc, lp);
}

// ---------------- image path pass 1: scores, per-row argmax+val, norms, per-slot col max ----------------
__global__ __launch_bounds__(256) void k_B1(const float* __restrict__ I,
                                            const float* __restrict__ C,
                                            float* __restrict__ sia,
                                            int* __restrict__ aw,
                                            float* __restrict__ nr,
                                            u32* __restrict__ cmax) {
    __shared__ __align__(16) float t_flat[TB * DIM];
    __shared__ float sp[TB * MSLOT];
    __shared__ float nrm[TB];
    const int tid = threadIdx.x;
    const size_t base = (size_t)blockIdx.x * (TB * DIM);

    const float4* src = (const float4*)(I + base);
    float4* dst = (float4*)t_flat;
    for (int v = tid; v < TB * DIM / 4; v += 256) dst[v] = src[v];
    __syncthreads();
    {
        int tt = tid >> 4, l = tid & 15;
        float ss = 0.f;
        for (int c = l; c < DIM; c += 16) { float x = t_flat[tt * DIM + c]; ss += x * x; }
        ss += __shfl_xor(ss, 8, 16);
        ss += __shfl_xor(ss, 4, 16);
        ss += __shfl_xor(ss, 2, 16);
        ss += __shfl_xor(ss, 1, 16);
        if (l == 0) nrm[tt] = sqrtf(ss);
    }
    __syncthreads();
    for (int pr = tid; pr < TB * MSLOT; pr += 256) {
        int tt = pr / MSLOT, j = pr - tt * MSLOT;
        const float4* c4 = (const float4*)(C + j * DIM);
        const float4* tp = (const float4*)&t_flat[tt * DIM];
        float acc = 0.f;
        for (int kc = 0; kc < DIM / 4; kc++) {
            float4 cv = c4[kc], q = tp[kc];
            acc += cv.x * q.x + cv.y * q.y + cv.z * q.z + cv.w * q.w;
        }
        sp[pr] = acc / fmaxf(nrm[tt], 1e-12f);
    }
    __syncthreads();
    if (tid < TB) {
        int tok = blockIdx.x * TB + tid;
        nr[tok] = nrm[tid];
        float best = sp[tid * MSLOT];
        int bj = 0;
        for (int j = 1; j < MSLOT; j++) {
            float v = sp[tid * MSLOT + j];
            if (v > best) { best = v; bj = j; }   // first-max tie-break like argmax
        }
        aw[tok] = bj;
        sia[tok] = best;
    }
    if (tid < MSLOT) {
        float m = sp[tid];
        for (int tt = 1; tt < TB; tt++) m = fmaxf(m, sp[tt * MSLOT + tid]);
        atomicMax(&cmax[tid], f2sort(m));
    }
}

// ---------------- image path pass 2: scatter EMA accumulation (LDS per-block, column-owned) ----------------
#define B2_BLOCKS 512
#define B2_CHUNK (NTOK / B2_BLOCKS)
__global__ __launch_bounds__(256) void k_B2(const float* __restrict__ I,
                                            const float* __restrict__ sia,
                                            const int* __restrict__ aw,
                                            const float* __restrict__ nr,
                                            const u32* __restrict__ cmax,
                                            float* __restrict__ seg,
                                            float* __restrict__ cnt) {
    __shared__ float segb[MSLOT * DIM];
    __shared__ float cntb[MSLOT];
    __shared__ float cm[MSLOT];
    const int tid = threadIdx.x;
    for (int i = tid; i < MSLOT * DIM; i += 256) segb[i] = 0.f;
    if (tid < MSLOT) { cntb[tid] = 0.f; cm[tid] = sort2f(cmax[tid]); }
    __syncthreads();
    const int i0 = blockIdx.x * B2_CHUNK;
    const float2* ip = (const float2*)I;
    for (int t = 0; t < B2_CHUNK; t++) {
        int i = i0 + t;
        int a = aw[i];
        float scale = expf(sia[i] - cm[a]) / fmaxf(nr[i], 1e-12f);
        float2 v = ip[(size_t)i * (DIM / 2) + tid];    // cols 2*tid, 2*tid+1 (coalesced)
        segb[a * DIM + 2 * tid]     += scale * v.x;
        segb[a * DIM + 2 * tid + 1] += scale * v.y;
        if (tid == 0) cntb[a] += 1.0f;
        // no barrier needed: every thread exclusively owns its two columns
    }
    __syncthreads();
    for (int idx = tid; idx < MSLOT * DIM; idx += 256) atomicAdd(&seg[idx], segb[idx]);
    if (tid < MSLOT) atomicAdd(&cnt[tid], cntb[tid]);
}

// ---------------- finalize: upd rows + loss scalar ----------------
__global__ __launch_bounds__(256) void k_fin(const float* __restrict__ C,
                                             const float* __restrict__ seg,
                                             const float* __restrict__ cnt,
                                             const float* __restrict__ loss_acc,
                                             float* __restrict__ out) {
    const int b = blockIdx.x, tid = threadIdx.x;
    if (b == MSLOT) {
        if (tid == 0) out[(size_t)NTOK * DIM] = loss_acc[0] * (1.0f / 67108864.0f);
        return;
    }
    __shared__ float wred[4];
    __shared__ float nrm_s;
    const int c0 = 2 * tid;
    float ca0 = C[b * DIM + c0];
    float ca1 = C[b * DIM + c0 + 1];
    bool has = cnt[b] > 0.f;
    float v0 = has ? MOMENTUM * ca0 + (1.0f - MOMENTUM) * seg[b * DIM + c0]     : ca0;
    float v1 = has ? MOMENTUM * ca1 + (1.0f - MOMENTUM) * seg[b * DIM + c0 + 1] : ca1;
    float ss = v0 * v0 + v1 * v1;
    ss += __shfl_xor(ss, 32, 64); ss += __shfl_xor(ss, 16, 64);
    ss += __shfl_xor(ss, 8, 64);  ss += __shfl_xor(ss, 4, 64);
    ss += __shfl_xor(ss, 2, 64);  ss += __shfl_xor(ss, 1, 64);
    if ((tid & 63) == 0) wred[tid >> 6] = ss;
    __syncthreads();
    if (tid == 0) nrm_s = sqrtf(wred[0] + wred[1] + wred[2] + wred[3]);
    __syncthreads();
    float inv = 1.0f / fmaxf(nrm_s, 1e-12f);
    size_t ob = (size_t)NTOK * DIM + 1 + (size_t)b * DIM;
    out[ob + c0]     = v0 * inv;
    out[ob + c0 + 1] = v1 * inv;
}

// ---------------- workspace layout (floats) ----------------
#define OFF_G    0
#define OFF_SEG  12800
#define OFF_CNT  25600
#define OFF_CMAX 25625
#define OFF_LOSS 25650
#define OFF_SIA  25651
#define OFF_A    (25651 + NTOK)
#define OFF_NRM  (25651 + 2 * NTOK)

extern "C" void kernel_launch(void* const* d_in, const int* in_sizes, int n_in,
                              void* d_out, int out_size, void* d_ws, size_t ws_size,
                              hipStream_t stream) {
    const float* T = (const float*)d_in[0];   // text_token  [N, D] f32
    const float* I = (const float*)d_in[1];   // image_token [N, D] f32
    const float* W = (const float*)d_in[2];   // W [D, 2D] f32
    const float* C = (const float*)d_in[3];   // cache [M, D] f32
    float* out = (float*)d_out;

    float* ws   = (float*)d_ws;
    float* G    = ws + OFF_G;
    float* seg  = ws + OFF_SEG;
    float* cnt  = ws + OFF_CNT;
    u32*   cmax = (u32*)(ws + OFF_CMAX);
    float* loss = ws + OFF_LOSS;
    float* sia  = ws + OFF_SIA;
    int*   aw   = (int*)(ws + OFF_A);
    float* nr   = ws + OFF_NRM;

    // zero seg/cnt/cmax(sortable -inf = 0)/loss in one contiguous memset
    hipMemsetAsync(seg, 0, (size_t)(12800 + 25 + 25 + 1) * sizeof(float), stream);

    hipLaunchKernelGGL(k_G,   dim3(50),           dim3(256), 0, stream, W, C, G);
    hipLaunchKernelGGL(k_A,   dim3(NTOK / TB),    dim3(256), 0, stream, T, W, C, G, out, loss);
    hipLaunchKernelGGL(k_B1,  dim3(NTOK / TB),    dim3(256), 0, stream, I, C, sia, aw, nr, cmax);
    hipLaunchKernelGGL(k_B2,  dim3(B2_BLOCKS),    dim3(256), 0, stream, I, sia, aw, nr, cmax, seg, cnt);
    hipLaunchKernelGGL(k_fin, dim3(MSLOT + 1),    dim3(256), 0, stream, C, seg, cnt, loss, out);
}